// Round 1
// baseline (6560.996 us; speedup 1.0000x reference)
//
#include <hip/hip_runtime.h>
#include <stdint.h>

typedef unsigned short u16;
typedef unsigned int u32;
typedef __attribute__((ext_vector_type(8))) short bf16x8;
typedef __attribute__((ext_vector_type(4))) float f32x4;

#define DEV __device__ __forceinline__

#define NB 512   // batch
#define NT 64    // time
#define NE 1536  // embed
#define NH 512   // hid == deter
#define NS 32    // stoch

// ---- workspace layout (bytes) ----
static constexpr size_t OFF_EOBS   = 0;                                    // [T][B][512] f32
static constexpr size_t OFF_DETERF = OFF_EOBS + (size_t)NT*NB*512*4;       // [2][B][512] f32
static constexpr size_t OFF_STOCHF = OFF_DETERF + (size_t)2*NB*512*4;      // [B][32] f32
static constexpr size_t OFF_D0     = OFF_STOCHF + (size_t)NB*32*4;         // [512] f32
static constexpr size_t OFF_S0     = OFF_D0 + 512*4;                       // [32] f32 (pad 256)
static constexpr size_t OFF_XD     = OFF_S0 + 256;                         // [2][B][1024] bf16 (x | deter)
static constexpr size_t OFF_WINPT  = OFF_XD + (size_t)2*NB*1024*2;         // [512][64] bf16 (K padded 38->64)
static constexpr size_t OFF_WGRUT  = OFF_WINPT + (size_t)512*64*2;         // [1536][1024] bf16
static constexpr size_t OFF_WIMGT  = OFF_WGRUT + (size_t)1536*1024*2;      // [512][512]
static constexpr size_t OFF_WOBSDT = OFF_WIMGT + (size_t)512*512*2;        // [512][512]
static constexpr size_t OFF_WOBSET = OFF_WOBSDT + (size_t)512*512*2;       // [512][1536]
static constexpr size_t OFF_WIMST  = OFF_WOBSET + (size_t)512*1536*2;      // [64][512]
static constexpr size_t OFF_WOSTT  = OFF_WIMST + (size_t)64*512*2;         // [64][512]
static constexpr size_t WS_NEED    = OFF_WOSTT + (size_t)64*512*2;         // ~77.3 MB

DEV u16 f2b(float f) {
  u32 u = __builtin_bit_cast(u32, f);
  u32 r = (u + 0x7FFFu + ((u >> 16) & 1u)) >> 16;
  return (u16)r;
}
DEV float b2f(u16 h) { u32 u = (u32)h << 16; return __builtin_bit_cast(float, u); }
DEV u32 pk2(float a, float b) { return (u32)f2b(a) | ((u32)f2b(b) << 16); }
DEV float sigf(float x) { return 1.f / (1.f + __expf(-x)); }
DEV float siluf(float x) { return x * sigf(x); }
DEV float softplusf(float x) { return (x > 20.f) ? x : log1pf(__expf(x)); }
DEV f32x4 mfma16(bf16x8 a, bf16x8 b, f32x4 c) {
  return __builtin_amdgcn_mfma_f32_16x16x32_bf16(a, b, c, 0, 0, 0);
}

// ---------------- weight conversion (f32 -> transposed [N][K] bf16) ----------------
__global__ __launch_bounds__(256) void k_convert(
    const float* __restrict__ W_inp, const float* __restrict__ W_gru,
    const float* __restrict__ W_img, const float* __restrict__ W_obs,
    const float* __restrict__ W_ims, const float* __restrict__ W_ostat,
    char* __restrict__ ws) {
  u16* winpT  = (u16*)(ws + OFF_WINPT);
  u16* wgruT  = (u16*)(ws + OFF_WGRUT);
  u16* wimgT  = (u16*)(ws + OFF_WIMGT);
  u16* wobsdT = (u16*)(ws + OFF_WOBSDT);
  u16* wobseT = (u16*)(ws + OFF_WOBSET);
  u16* wimsT  = (u16*)(ws + OFF_WIMST);
  u16* wostT  = (u16*)(ws + OFF_WOSTT);
  int i = blockIdx.x * 256 + threadIdx.x;
  if (i < 32768) { int n = i >> 6, k = i & 63; winpT[i] = (k < 38) ? f2b(W_inp[k*512 + n]) : (u16)0; return; }
  i -= 32768;
  if (i < 1572864) { int n = i >> 10, k = i & 1023; wgruT[i] = f2b(W_gru[(size_t)k*1536 + n]); return; }
  i -= 1572864;
  if (i < 262144) { int n = i >> 9, k = i & 511; wimgT[i] = f2b(W_img[k*512 + n]); return; }
  i -= 262144;
  if (i < 262144) { int n = i >> 9, k = i & 511; wobsdT[i] = f2b(W_obs[k*512 + n]); return; }
  i -= 262144;
  if (i < 786432) { int n = i / 1536, e = i - n*1536; wobseT[i] = f2b(W_obs[(size_t)(512 + e)*512 + n]); return; }
  i -= 786432;
  if (i < 32768) { int n = i >> 9, k = i & 511; wimsT[i] = f2b(W_ims[k*64 + n]); return; }
  i -= 32768;
  { int n = i >> 9, k = i & 511; wostT[i] = f2b(W_ostat[k*64 + n]); }
}

// ---------------- initial state: deter0 = tanh(W_init); stoch0 = mean of prior(img_out(deter0)) ----------------
__global__ __launch_bounds__(256) void k_init_a(
    const float* __restrict__ W_init, const float* __restrict__ W_img,
    const float* __restrict__ g_img, const float* __restrict__ b_img,
    const float* __restrict__ W_ims, const float* __restrict__ b_ims,
    char* __restrict__ ws) {
  __shared__ float DL[512];
  __shared__ float HL[512];
  __shared__ float RED[256];
  float* d0 = (float*)(ws + OFF_D0);
  float* s0 = (float*)(ws + OFF_S0);
  const int t = threadIdx.x;
  for (int j = t; j < 512; j += 256) { float v = tanhf(W_init[j]); DL[j] = v; d0[j] = v; }
  __syncthreads();
  float pre0 = 0.f, pre1 = 0.f;
  for (int k = 0; k < 512; ++k) {
    float dv = DL[k];
    pre0 += dv * W_img[k*512 + t];
    pre1 += dv * W_img[k*512 + t + 256];
  }
  RED[t] = pre0 + pre1;
  __syncthreads();
  for (int s = 128; s > 0; s >>= 1) { if (t < s) RED[t] += RED[t + s]; __syncthreads(); }
  float m = RED[0] * (1.f/512.f);
  __syncthreads();
  RED[t] = pre0*pre0 + pre1*pre1;
  __syncthreads();
  for (int s = 128; s > 0; s >>= 1) { if (t < s) RED[t] += RED[t + s]; __syncthreads(); }
  float var = RED[0] * (1.f/512.f) - m*m;
  float inv = rsqrtf(var + 1e-3f);
  HL[t]       = siluf((pre0 - m)*inv*g_img[t] + b_img[t]);
  HL[t + 256] = siluf((pre1 - m)*inv*g_img[t+256] + b_img[t+256]);
  __syncthreads();
  if (t < 32) {
    float s = 0.f;
    for (int k = 0; k < 512; ++k) s += HL[k] * W_ims[k*64 + t];
    s0[t] = s + b_ims[t];
  }
}

__global__ __launch_bounds__(256) void k_init_b(char* __restrict__ ws) {
  const float* d0 = (const float*)(ws + OFF_D0);
  const float* s0 = (const float*)(ws + OFF_S0);
  float* detf0 = (float*)(ws + OFF_DETERF);     // slot 0
  float* stochf = (float*)(ws + OFF_STOCHF);
  u16* xd0 = (u16*)(ws + OFF_XD);               // slot 0
  int idx = blockIdx.x * 256 + threadIdx.x;     // < 262144
  int b = idx >> 9, j = idx & 511;
  float v = d0[j];
  detf0[idx] = v;
  xd0[(size_t)b*1024 + 512 + j] = f2b(v);
  if (j < 32) stochf[b*32 + j] = s0[j];
}

// ---------------- phase 1: E_obs[t][b][:] = embed[b][t][:] @ W_obs[512:,:] ----------------
__global__ __launch_bounds__(256) void k_phase1(
    const float* __restrict__ embed, char* __restrict__ ws) {
  const u16* wobseT = (const u16*)(ws + OFF_WOBSET);
  float* eobs = (float*)(ws + OFF_EOBS);
  __shared__ u16 AL[128 * 40];
  const int tid = threadIdx.x;
  const int nb = blockIdx.x;   // 0..3  (fast -> same-mb blocks co-resident, A L2-reused)
  const int mb = blockIdx.y;   // 0..255
  const int w = tid >> 6, l = tid & 63, l15 = l & 15, lk = l >> 4;
  const int wr = w >> 1, wc = w & 1;
  const f32x4 fz = {0.f, 0.f, 0.f, 0.f};
  f32x4 acc[4][4];
  for (int a = 0; a < 4; ++a) for (int c = 0; c < 4; ++c) acc[a][c] = fz;
  const int srow = tid >> 1, sko = (tid & 1) << 4;
  const float* srcbase = embed + (size_t)(mb*128 + srow)*1536 + sko;
  u16* dst = AL + srow*40 + sko;
  for (int kk = 0; kk < 48; ++kk) {
    __syncthreads();
    {
      const float* src = srcbase + kk*32;
      float4 v0 = *(const float4*)(src);
      float4 v1 = *(const float4*)(src + 4);
      float4 v2 = *(const float4*)(src + 8);
      float4 v3 = *(const float4*)(src + 12);
      uint4 q0, q1;
      q0.x = pk2(v0.x, v0.y); q0.y = pk2(v0.z, v0.w);
      q0.z = pk2(v1.x, v1.y); q0.w = pk2(v1.z, v1.w);
      q1.x = pk2(v2.x, v2.y); q1.y = pk2(v2.z, v2.w);
      q1.z = pk2(v3.x, v3.y); q1.w = pk2(v3.z, v3.w);
      *(uint4*)(dst) = q0;
      *(uint4*)(dst + 8) = q1;
    }
    __syncthreads();
    bf16x8 af[4], bf[4];
    for (int ar = 0; ar < 4; ++ar)
      af[ar] = *(const bf16x8*)(AL + (wr*64 + ar*16 + l15)*40 + lk*8);
    for (int ac = 0; ac < 4; ++ac) {
      int col = nb*128 + wc*64 + ac*16 + l15;
      bf[ac] = *(const bf16x8*)(wobseT + (size_t)col*1536 + kk*32 + lk*8);
    }
    for (int ar = 0; ar < 4; ++ar)
      for (int ac = 0; ac < 4; ++ac)
        acc[ar][ac] = mfma16(af[ar], bf[ac], acc[ar][ac]);
  }
  for (int ar = 0; ar < 4; ++ar)
    for (int ac = 0; ac < 4; ++ac) {
      int col = nb*128 + wc*64 + ac*16 + l15;
      for (int r = 0; r < 4; ++r) {
        int row = mb*128 + wr*64 + ar*16 + lk*4 + r;  // row = b*64 + t
        int bb = row >> 6, tt = row & 63;
        eobs[((size_t)tt*512 + bb)*512 + col] = acc[ar][ac][r];
      }
    }
}

// ---------------- per-step K1: x = silu(LN(concat(stoch,a)@W_inp)) ----------------
__global__ __launch_bounds__(256) void k_inp(
    const float* __restrict__ action, const float* __restrict__ reset,
    const float* __restrict__ g_inp, const float* __restrict__ b_inp,
    char* __restrict__ ws, int tstep, int sin) {
  const float* stochf = (const float*)(ws + OFF_STOCHF);
  const float* s0 = (const float*)(ws + OFF_S0);
  const u16* winpT = (const u16*)(ws + OFF_WINPT);
  u16* xd = (u16*)(ws + OFF_XD) + (size_t)sin * NB * 1024;
  __shared__ u16 SA[16 * 72];
  __shared__ float LNB[4][16][2];
  const int tid = threadIdx.x;
  const int mb = blockIdx.x;  // 0..31
  const int w = tid >> 6, l = tid & 63, l15 = l & 15, lk = l >> 4;
  {
    int row = tid >> 4, ko = (tid & 15) * 4;
    int brow = mb*16 + row;
    float r = reset[(size_t)brow*NT + tstep];
    float onem = 1.f - r;
    float v[4];
    for (int i = 0; i < 4; ++i) {
      int k = ko + i;
      float x;
      if (k < 32)      x = stochf[brow*32 + k]*onem + s0[k]*r;
      else if (k < 38) x = action[((size_t)brow*NT + tstep)*6 + (k - 32)] * onem;
      else             x = 0.f;
      v[i] = x;
    }
    uint2 q; q.x = pk2(v[0], v[1]); q.y = pk2(v[2], v[3]);
    *(uint2*)(SA + row*72 + ko) = q;
  }
  __syncthreads();
  const f32x4 fz = {0.f,0.f,0.f,0.f};
  f32x4 acc[8];
  for (int f = 0; f < 8; ++f) acc[f] = fz;
  for (int kk = 0; kk < 2; ++kk) {
    bf16x8 af = *(const bf16x8*)(SA + l15*72 + kk*32 + lk*8);
    for (int f = 0; f < 8; ++f) {
      int col = w*128 + f*16 + l15;
      bf16x8 bf = *(const bf16x8*)(winpT + col*64 + kk*32 + lk*8);
      acc[f] = mfma16(af, bf, acc[f]);
    }
  }
  for (int r = 0; r < 4; ++r) {
    float s1 = 0.f, s2 = 0.f;
    for (int f = 0; f < 8; ++f) { float v = acc[f][r]; s1 += v; s2 += v*v; }
    for (int d = 1; d < 16; d <<= 1) { s1 += __shfl_xor(s1, d); s2 += __shfl_xor(s2, d); }
    if (l15 == 0) { LNB[w][lk*4 + r][0] = s1; LNB[w][lk*4 + r][1] = s2; }
  }
  __syncthreads();
  float mr[4], ir[4];
  for (int r = 0; r < 4; ++r) {
    int row = lk*4 + r;
    float S1 = LNB[0][row][0] + LNB[1][row][0] + LNB[2][row][0] + LNB[3][row][0];
    float S2 = LNB[0][row][1] + LNB[1][row][1] + LNB[2][row][1] + LNB[3][row][1];
    float m = S1 * (1.f/512.f);
    float var = S2 * (1.f/512.f) - m*m;
    mr[r] = m; ir[r] = rsqrtf(var + 1e-3f);
  }
  for (int f = 0; f < 8; ++f) {
    int col = w*128 + f*16 + l15;
    float gg = g_inp[col], bb = b_inp[col];
    for (int r = 0; r < 4; ++r) {
      float v = siluf((acc[f][r] - mr[r]) * ir[r] * gg + bb);
      int brow = mb*16 + lk*4 + r;
      xd[(size_t)brow*1024 + col] = f2b(v);
    }
  }
}

// ---------------- per-step K2: GRU GEMM + gates -> deter_n ----------------
__global__ __launch_bounds__(256) void k_gru(
    const float* __restrict__ reset, float* __restrict__ out,
    char* __restrict__ ws, int tstep, int sin) {
  const int sout = sin ^ 1;
  const u16* xdin = (const u16*)(ws + OFF_XD) + (size_t)sin * NB * 1024;
  u16* xdout = (u16*)(ws + OFF_XD) + (size_t)sout * NB * 1024;
  const float* detin = (const float*)(ws + OFF_DETERF) + (size_t)sin * NB * 512;
  float* detout = (float*)(ws + OFF_DETERF) + (size_t)sout * NB * 512;
  const float* d0 = (const float*)(ws + OFF_D0);
  const u16* wgruT = (const u16*)(ws + OFF_WGRUT);
  __shared__ u16 AL[64 * 72];
  const int tid = threadIdx.x;
  const int mb = blockIdx.x;   // 0..7
  const int g = blockIdx.y;    // 0..7 gate-column chunk
  const int w = tid >> 6, l = tid & 63, l15 = l & 15, lk = l >> 4;
  const f32x4 fz = {0.f,0.f,0.f,0.f};
  f32x4 acc[12];
  for (int f = 0; f < 12; ++f) acc[f] = fz;
  const int srow = tid >> 2, sko = (tid & 3) * 16;
  const int sbrow = mb*64 + srow;
  const u16* sbase = xdin + (size_t)sbrow*1024 + sko;
  u16* sdst = AL + srow*72 + sko;
  const float rstage = reset[(size_t)sbrow*NT + tstep];
  for (int kk = 0; kk < 16; ++kk) {
    __syncthreads();
    {
      uint4 v0 = *(const uint4*)(sbase + kk*64);
      uint4 v1 = *(const uint4*)(sbase + kk*64 + 8);
      if (kk >= 8 && rstage != 0.f) {   // deter half: blend with deter0
        float onem = 1.f - rstage;
        const float* dd = d0 + kk*64 + sko - 512;
        u16* pp = (u16*)&v0;
        for (int i = 0; i < 8; ++i) pp[i] = f2b(b2f(pp[i])*onem + dd[i]*rstage);
        pp = (u16*)&v1;
        for (int i = 0; i < 8; ++i) pp[i] = f2b(b2f(pp[i])*onem + dd[8+i]*rstage);
      }
      *(uint4*)(sdst) = v0;
      *(uint4*)(sdst + 8) = v1;
    }
    __syncthreads();
    for (int ks = 0; ks < 2; ++ks) {
      bf16x8 af = *(const bf16x8*)(AL + (w*16 + l15)*72 + ks*32 + lk*8);
      bf16x8 bf[12];
      for (int f = 0; f < 12; ++f) {
        int colrow = (f >> 2)*512 + g*64 + (f & 3)*16 + l15;
        bf[f] = *(const bf16x8*)(wgruT + (size_t)colrow*1024 + kk*64 + ks*32 + lk*8);
      }
      for (int f = 0; f < 12; ++f) acc[f] = mfma16(af, bf[f], acc[f]);
    }
  }
  for (int r = 0; r < 4; ++r) {
    int brow = mb*64 + w*16 + lk*4 + r;
    float rb = reset[(size_t)brow*NT + tstep];
    for (int n = 0; n < 4; ++n) {
      int j = g*64 + n*16 + l15;
      float dold = detin[(size_t)brow*512 + j];
      if (rb != 0.f) dold = dold*(1.f - rb) + d0[j]*rb;
      float rg = sigf(acc[n][r]);
      float ca = tanhf(rg * acc[4 + n][r]);
      float up = sigf(acc[8 + n][r] - 1.f);
      float dn = up*ca + (1.f - up)*dold;
      detout[(size_t)brow*512 + j] = dn;
      xdout[(size_t)brow*1024 + 512 + j] = f2b(dn);
      out[((size_t)brow*NT + tstep)*704 + 192 + j] = dn;
    }
  }
}

// ---------------- per-step K3: posterior: h=silu(LN(deter@Wd + E_obs)); q=h@W_ostat; sample ----------------
__global__ __launch_bounds__(256) void k_obs(
    const float* __restrict__ g_obs, const float* __restrict__ b_obs,
    const float* __restrict__ b_ostat, const float* __restrict__ npost,
    float* __restrict__ out, char* __restrict__ ws, int tstep, int sin) {
  const int sout = sin ^ 1;
  const u16* xdn = (const u16*)(ws + OFF_XD) + (size_t)sout * NB * 1024;  // deter_n bf16
  const float* eobs = (const float*)(ws + OFF_EOBS);
  const u16* wobsdT = (const u16*)(ws + OFF_WOBSDT);
  const u16* wostT = (const u16*)(ws + OFF_WOSTT);
  float* stochf = (float*)(ws + OFF_STOCHF);
  __shared__ u16 AL[16 * 40];
  __shared__ u16 HL[16 * 520];
  __shared__ float LNB[4][16][2];
  __shared__ float STL[16 * 64];
  const int tid = threadIdx.x;
  const int mb = blockIdx.x;   // 0..31
  const int w = tid >> 6, l = tid & 63, l15 = l & 15, lk = l >> 4;
  const f32x4 fz = {0.f,0.f,0.f,0.f};
  f32x4 acc[8];
  for (int f = 0; f < 8; ++f) acc[f] = fz;
  const int srow = tid >> 4, sko = (tid & 15) * 2;
  const u16* sbase = xdn + (size_t)(mb*16 + srow)*1024 + 512 + sko;
  u16* sdst = AL + srow*40 + sko;
  for (int kk = 0; kk < 16; ++kk) {
    __syncthreads();
    *(u32*)sdst = *(const u32*)(sbase + kk*32);
    __syncthreads();
    bf16x8 af = *(const bf16x8*)(AL + l15*40 + lk*8);
    for (int f = 0; f < 8; ++f) {
      int col = w*128 + f*16 + l15;
      bf16x8 bf = *(const bf16x8*)(wobsdT + (size_t)col*512 + kk*32 + lk*8);
      acc[f] = mfma16(af, bf, acc[f]);
    }
  }
  for (int f = 0; f < 8; ++f) {
    int col = w*128 + f*16 + l15;
    for (int r = 0; r < 4; ++r) {
      int brow = mb*16 + lk*4 + r;
      acc[f][r] += eobs[((size_t)tstep*512 + brow)*512 + col];
    }
  }
  for (int r = 0; r < 4; ++r) {
    float s1 = 0.f, s2 = 0.f;
    for (int f = 0; f < 8; ++f) { float v = acc[f][r]; s1 += v; s2 += v*v; }
    for (int d = 1; d < 16; d <<= 1) { s1 += __shfl_xor(s1, d); s2 += __shfl_xor(s2, d); }
    if (l15 == 0) { LNB[w][lk*4 + r][0] = s1; LNB[w][lk*4 + r][1] = s2; }
  }
  __syncthreads();
  float mr[4], ir[4];
  for (int r = 0; r < 4; ++r) {
    int row = lk*4 + r;
    float S1 = LNB[0][row][0] + LNB[1][row][0] + LNB[2][row][0] + LNB[3][row][0];
    float S2 = LNB[0][row][1] + LNB[1][row][1] + LNB[2][row][1] + LNB[3][row][1];
    float m = S1 * (1.f/512.f);
    float var = S2 * (1.f/512.f) - m*m;
    mr[r] = m; ir[r] = rsqrtf(var + 1e-3f);
  }
  for (int f = 0; f < 8; ++f) {
    int col = w*128 + f*16 + l15;
    float gg = g_obs[col], bb = b_obs[col];
    for (int r = 0; r < 4; ++r) {
      float v = siluf((acc[f][r] - mr[r]) * ir[r] * gg + bb);
      HL[(lk*4 + r)*520 + col] = f2b(v);
    }
  }
  __syncthreads();
  f32x4 q = fz;
  for (int kk = 0; kk < 16; ++kk) {
    bf16x8 af = *(const bf16x8*)(HL + l15*520 + kk*32 + lk*8);
    bf16x8 bf = *(const bf16x8*)(wostT + (size_t)(w*16 + l15)*512 + kk*32 + lk*8);
    q = mfma16(af, bf, q);
  }
  float bia = b_ostat[w*16 + l15];
  for (int r = 0; r < 4; ++r)
    STL[(lk*4 + r)*64 + w*16 + l15] = q[r] + bia;
  __syncthreads();
  for (int it = tid; it < 512; it += 256) {
    int row = it >> 5, i = it & 31;
    int brow = mb*16 + row;
    float qm = STL[row*64 + i];
    float qs = softplusf(STL[row*64 + 32 + i]) + 0.1f;
    float ns = npost[((size_t)tstep*512 + brow)*32 + i];
    float qst = qm + qs*ns;
    size_t ob = ((size_t)brow*NT + tstep)*704;
    out[ob + i] = qm;
    out[ob + 32 + i] = qs;
    out[ob + 64 + i] = qst;
    stochf[brow*32 + i] = qst;
  }
}

// ---------------- phase 3: prior branch for all (b,t) ----------------
__global__ __launch_bounds__(256) void k_p3(
    const float* __restrict__ g_img, const float* __restrict__ b_img,
    const float* __restrict__ b_ims, const float* __restrict__ nprior,
    float* __restrict__ out, char* __restrict__ ws) {
  const u16* wimgT = (const u16*)(ws + OFF_WIMGT);
  const u16* wimsT = (const u16*)(ws + OFF_WIMST);
  __shared__ u16 AL[32 * 40];
  __shared__ u16 HL[32 * 520];
  __shared__ float LNB[4][32][2];
  __shared__ float STL[32 * 64];
  const int tid = threadIdx.x;
  const int mb = blockIdx.x;   // 0..1023
  const int w = tid >> 6, l = tid & 63, l15 = l & 15, lk = l >> 4;
  const f32x4 fz = {0.f,0.f,0.f,0.f};
  f32x4 acc[2][8];
  for (int rb = 0; rb < 2; ++rb) for (int f = 0; f < 8; ++f) acc[rb][f] = fz;
  const int srow = tid >> 3, sko = (tid & 7) * 4;
  const float* sbase = out + (size_t)(mb*32 + srow)*704 + 192 + sko;  // deter_n
  u16* sdst = AL + srow*40 + sko;
  for (int kk = 0; kk < 16; ++kk) {
    __syncthreads();
    {
      float4 v = *(const float4*)(sbase + kk*32);
      uint2 q; q.x = pk2(v.x, v.y); q.y = pk2(v.z, v.w);
      *(uint2*)sdst = q;
    }
    __syncthreads();
    bf16x8 af0 = *(const bf16x8*)(AL + l15*40 + lk*8);
    bf16x8 af1 = *(const bf16x8*)(AL + (16 + l15)*40 + lk*8);
    for (int f = 0; f < 8; ++f) {
      int col = w*128 + f*16 + l15;
      bf16x8 bf = *(const bf16x8*)(wimgT + (size_t)col*512 + kk*32 + lk*8);
      acc[0][f] = mfma16(af0, bf, acc[0][f]);
      acc[1][f] = mfma16(af1, bf, acc[1][f]);
    }
  }
  for (int rb = 0; rb < 2; ++rb) {
    for (int r = 0; r < 4; ++r) {
      float s1 = 0.f, s2 = 0.f;
      for (int f = 0; f < 8; ++f) { float v = acc[rb][f][r]; s1 += v; s2 += v*v; }
      for (int d = 1; d < 16; d <<= 1) { s1 += __shfl_xor(s1, d); s2 += __shfl_xor(s2, d); }
      if (l15 == 0) { LNB[w][rb*16 + lk*4 + r][0] = s1; LNB[w][rb*16 + lk*4 + r][1] = s2; }
    }
  }
  __syncthreads();
  for (int rb = 0; rb < 2; ++rb) {
    float mr[4], ir[4];
    for (int r = 0; r < 4; ++r) {
      int row = rb*16 + lk*4 + r;
      float S1 = LNB[0][row][0] + LNB[1][row][0] + LNB[2][row][0] + LNB[3][row][0];
      float S2 = LNB[0][row][1] + LNB[1][row][1] + LNB[2][row][1] + LNB[3][row][1];
      float m = S1 * (1.f/512.f);
      float var = S2 * (1.f/512.f) - m*m;
      mr[r] = m; ir[r] = rsqrtf(var + 1e-3f);
    }
    for (int f = 0; f < 8; ++f) {
      int col = w*128 + f*16 + l15;
      float gg = g_img[col], bb = b_img[col];
      for (int r = 0; r < 4; ++r) {
        float v = siluf((acc[rb][f][r] - mr[r]) * ir[r] * gg + bb);
        HL[(rb*16 + lk*4 + r)*520 + col] = f2b(v);
      }
    }
  }
  __syncthreads();
  f32x4 q0 = fz, q1 = fz;
  for (int kk = 0; kk < 16; ++kk) {
    bf16x8 bf = *(const bf16x8*)(wimsT + (size_t)(w*16 + l15)*512 + kk*32 + lk*8);
    bf16x8 af0 = *(const bf16x8*)(HL + l15*520 + kk*32 + lk*8);
    bf16x8 af1 = *(const bf16x8*)(HL + (16 + l15)*520 + kk*32 + lk*8);
    q0 = mfma16(af0, bf, q0);
    q1 = mfma16(af1, bf, q1);
  }
  float bia = b_ims[w*16 + l15];
  for (int r = 0; r < 4; ++r) {
    STL[(lk*4 + r)*64 + w*16 + l15] = q0[r] + bia;
    STL[(16 + lk*4 + r)*64 + w*16 + l15] = q1[r] + bia;
  }
  __syncthreads();
  for (int it = tid; it < 1024; it += 256) {
    int row = it >> 5, i = it & 31;
    int grow = mb*32 + row;
    int bb = grow >> 6, tt = grow & 63;
    float pm = STL[row*64 + i];
    float ps = softplusf(STL[row*64 + 32 + i]) + 0.1f;
    float nr = nprior[((size_t)tt*512 + bb)*32 + i];
    float pst = pm + ps*nr;
    size_t ob = (size_t)grow*704;
    out[ob + 96 + i] = pm;
    out[ob + 128 + i] = ps;
    out[ob + 160 + i] = pst;
  }
}

extern "C" void kernel_launch(void* const* d_in, const int* in_sizes, int n_in,
                              void* d_out, int out_size, void* d_ws, size_t ws_size,
                              hipStream_t stream) {
  const float* embed   = (const float*)d_in[0];
  const float* action  = (const float*)d_in[1];
  const float* reset   = (const float*)d_in[2];
  const float* npost   = (const float*)d_in[3];
  const float* nprior  = (const float*)d_in[4];
  const float* W_inp   = (const float*)d_in[5];
  const float* g_inp   = (const float*)d_in[6];
  const float* b_inp   = (const float*)d_in[7];
  const float* W_gru   = (const float*)d_in[8];
  const float* W_img   = (const float*)d_in[9];
  const float* g_img   = (const float*)d_in[10];
  const float* b_img   = (const float*)d_in[11];
  const float* W_obs   = (const float*)d_in[12];
  const float* g_obs   = (const float*)d_in[13];
  const float* b_obs   = (const float*)d_in[14];
  const float* W_ims   = (const float*)d_in[15];
  const float* b_ims   = (const float*)d_in[16];
  const float* W_ostat = (const float*)d_in[17];
  const float* b_ostat = (const float*)d_in[18];
  const float* W_init  = (const float*)d_in[19];
  float* out = (float*)d_out;
  char* ws = (char*)d_ws;
  if (ws_size < WS_NEED) return;  // would fail validation loudly rather than corrupt memory

  k_convert<<<11648, 256, 0, stream>>>(W_inp, W_gru, W_img, W_obs, W_ims, W_ostat, ws);
  k_init_a<<<1, 256, 0, stream>>>(W_init, W_img, g_img, b_img, W_ims, b_ims, ws);
  k_init_b<<<1024, 256, 0, stream>>>(ws);
  k_phase1<<<dim3(4, 256), 256, 0, stream>>>(embed, ws);
  for (int t = 0; t < 64; ++t) {
    int sin = t & 1;
    k_inp<<<32, 256, 0, stream>>>(action, reset, g_inp, b_inp, ws, t, sin);
    k_gru<<<dim3(8, 8), 256, 0, stream>>>(reset, out, ws, t, sin);
    k_obs<<<32, 256, 0, stream>>>(g_obs, b_obs, b_ostat, npost, out, ws, t, sin);
  }
  k_p3<<<1024, 256, 0, stream>>>(g_img, b_img, b_ims, nprior, out, ws);
}